// Round 1
// baseline (431.050 us; speedup 1.0000x reference)
//
#include <hip/hip_runtime.h>
#include <math.h>
#include <stdint.h>

// Problem dims (fixed by reference setup_inputs)
#define BB 4
#define CC 8
#define PP 20
#define AA 30
#define SS 4
#define TT 2048
#define NB 18

#define TC 256                 // t-chunk staged in LDS
#define NCH (TT / TC)          // 8 chunks
#define NKEY (NB * NCH)        // 144 sort keys (bin-major, chunk-minor)
#define NTH 576                // 18 n-groups x 32 a-slots = 9 waves
#define AMP_STRIDE 33          // [TC][33] pad: bank = (tt + a) % 32, conflict-free

__global__ __launch_bounds__(NTH)
void mi_fused_kernel(const float* __restrict__ phase,
                     const float* __restrict__ amp,
                     float* __restrict__ out)
{
    // ent dead after scatter; amp chunk used only after -> union saves 16 KB
    __shared__ union {
        uint32_t ent[2 * TT];                 // 16 KB
        float    amp[TC * AMP_STRIDE];        // 33 KB
    } ua;
    __shared__ uint32_t sorted_e[2 * TT];     // 16 KB (t | w packed, key implicit)
    __shared__ uint32_t cnt[NKEY];
    __shared__ uint32_t offs[NKEY + 1];
    __shared__ uint32_t wpos[NKEY];
    __shared__ uint32_t scanb[NKEY];
    __shared__ float    dist_lds[NB * AA];

    const int tid = threadIdx.x;
    const int blk = blockIdx.x;
    const int s   = blk & (SS - 1);
    const int p   = (blk >> 2) % PP;
    const int bc  = blk / (SS * PP);          // b*CC + c

    const float* ph = phase + ((size_t)(bc * PP + p) * SS + s) * TT;
    const float* am = amp   + (size_t)bc * (AA * SS * TT) + (size_t)s * TT;
    float*       op = out   + ((size_t)bc * SS + s) * (PP * AA) + p * AA;

    const float PI_F  = 3.14159265358979323846f;
    const float INV_H = 2.8647913f;           // 18 / (2*pi)
    const float H     = 0.34906585f;          // 2*pi / 18
    const float INV_T = 100.0f;

    for (int i = tid; i < NKEY; i += NTH) cnt[i] = 0;

    // ---- Stage A: top-2 softmax weights per (t), packed key|t|w13 ----------
    for (int t = tid; t < TT; t += NTH) {
        float x = ph[t];
        float u = (x + PI_F) * INV_H;         // in [0, 18]
        int n0 = (int)floorf(u);
        n0 = n0 < 0 ? 0 : (n0 > NB - 1 ? NB - 1 : n0);
        float f  = u - (float)n0 - 0.5f;      // [-0.5, 0.5]
        float af = fabsf(f);
        int n1 = n0 + (f >= 0.0f ? 1 : -1);
        float e;
        if (n1 < 0) {                          // reference's unwrapped low edge:
            e = 0.0f; n1 = 1;                  // gap = h -> weight ~7e-16 -> drop
        } else {
            if (n1 == NB) n1 = 0;              // positive wrap: same gap formula
            e = expf(-(H * (1.0f - 2.0f * af)) * INV_T);
        }
        float w0 = 1.0f / (1.0f + e);
        float w1 = 1.0f - w0;
        uint32_t q0 = (uint32_t)(w0 * 8191.0f + 0.5f);   // always >= 4096
        uint32_t q1 = (uint32_t)(w1 * 8191.0f + 0.5f);   // 0 -> negligible, drop
        int ch = t / TC;
        uint32_t k0 = (uint32_t)(n0 * NCH + ch);
        uint32_t k1 = q1 ? (uint32_t)(n1 * NCH + ch) : 0xFFu;
        ua.ent[2 * t]     = (k0 << 24) | ((uint32_t)t << 13) | q0;
        ua.ent[2 * t + 1] = (k1 << 24) | ((uint32_t)t << 13) | q1;
    }
    __syncthreads();

    // ---- Stage B: counting sort by key -------------------------------------
    for (int j = tid; j < 2 * TT; j += NTH) {
        uint32_t k = ua.ent[j] >> 24;
        if (k != 0xFFu) atomicAdd(&cnt[k], 1u);
    }
    __syncthreads();

    uint32_t myc = 0;
    if (tid < NKEY) { myc = cnt[tid]; scanb[tid] = myc; }
    __syncthreads();
    for (int d = 1; d < NKEY; d <<= 1) {       // Hillis-Steele inclusive scan
        uint32_t addv = 0;
        if (tid < NKEY && tid >= d) addv = scanb[tid - d];
        __syncthreads();
        if (tid < NKEY) scanb[tid] += addv;
        __syncthreads();
    }
    if (tid < NKEY) {
        uint32_t ex = scanb[tid] - myc;
        offs[tid] = ex;
        wpos[tid] = ex;
    }
    if (tid == NKEY - 1) offs[NKEY] = scanb[NKEY - 1];
    __syncthreads();

    for (int j = tid; j < 2 * TT; j += NTH) {
        uint32_t e = ua.ent[j];
        uint32_t k = e >> 24;
        if (k != 0xFFu) {
            uint32_t dst = atomicAdd(&wpos[k], 1u);
            sorted_e[dst] = e & 0x00FFFFFFu;   // t(11) | w(13)
        }
    }
    __syncthreads();                           // ent dead; ua.amp reusable

    // ---- Stage C: segment accumulation, register acc per (n, a) ------------
    const int n = tid >> 5;                    // 0..17
    const int a = tid & 31;                    // 0..31, active a < 30
    const bool active = (a < AA);
    float acc = 0.0f;

    for (int c = 0; c < NCH; ++c) {
        // stage amp chunk t-major: coalesced global read, stride-33 LDS write
        for (int i = tid; i < AA * TC; i += NTH) {
            int la = i / TC;
            int tt = i - la * TC;
            ua.amp[tt * AMP_STRIDE + la] =
                am[(size_t)la * (SS * TT) + (size_t)(c * TC) + tt];
        }
        __syncthreads();
        if (active) {
            uint32_t j0 = offs[n * NCH + c];
            uint32_t j1 = offs[n * NCH + c + 1];
            float lacc = 0.0f;
            for (uint32_t j = j0; j < j1; ++j) {
                uint32_t e = sorted_e[j];                      // broadcast read
                int   tt = (int)((e >> 13) & (TC - 1));
                float w  = (float)(e & 0x1FFFu);
                lacc += w * ua.amp[tt * AMP_STRIDE + a];       // conflict-free
            }
            acc += lacc;
        }
        __syncthreads();
    }

    if (active) dist_lds[n * AA + a] = acc * (1.0f / 8191.0f);
    __syncthreads();

    // ---- Stage D: entropy epilogue, one thread per a -----------------------
    if (tid < AA) {
        float tot = 0.0f;
        for (int nn = 0; nn < NB; ++nn) tot += dist_lds[nn * AA + tid];
        float inv = 1.0f / (tot + 1e-10f);
        float ne = 0.0f;
        for (int nn = 0; nn < NB; ++nn) {
            float pv = dist_lds[nn * AA + tid] * inv;
            pv = fmaxf(pv, 1e-10f);
            ne += pv * logf(pv);
        }
        op[tid] = 1.0f + ne / logf(18.0f);
    }
}

extern "C" void kernel_launch(void* const* d_in, const int* in_sizes, int n_in,
                              void* d_out, int out_size, void* d_ws, size_t ws_size,
                              hipStream_t stream)
{
    const float* phase = (const float*)d_in[0];
    const float* amp   = (const float*)d_in[1];
    float* out = (float*)d_out;
    dim3 grid(BB * CC * PP * SS);   // 2560 blocks, one per (b,c,p,s)
    dim3 block(NTH);
    hipLaunchKernelGGL(mi_fused_kernel, grid, block, 0, stream,
                       phase, amp, out);
}

// Round 2
// 78.158 us; speedup vs baseline: 5.5151x; 5.5151x over previous
//
#include <hip/hip_runtime.h>
#include <math.h>
#include <stdint.h>

// Problem dims (fixed by reference setup_inputs)
#define BB 4
#define CC 8
#define PP 20
#define AA 30
#define SS 4
#define TT 2048
#define NB 18

#define TC 256                  // t-chunk (K-slab) per iteration
#define NCH (TT / TC)           // 8 chunks
#define NPG 10                  // p-groups of 2
#define WSTR 260                // f16 row stride: 520 B -> bank 2r%32, 2-way (free), 8B-aligned rows
#define NTH 256                 // 4 waves: (p_local, k_half)

typedef _Float16 half4_t __attribute__((ext_vector_type(4)));
typedef _Float16 half8_t __attribute__((ext_vector_type(8)));
typedef float f32x16 __attribute__((ext_vector_type(16)));

__global__ __launch_bounds__(NTH)
void mi_mfma_kernel(const float* __restrict__ phase,
                    const float* __restrict__ amp,
                    float* __restrict__ out)
{
    // W: dense weights [2 p][32 n-rows][WSTR t] f16 (rows 18..31 are a dump/garbage
    // zone: MFMA rows are independent, and acc rows >=18 are never extracted).
    __shared__ _Float16 Wl[2][32 * WSTR];     // 33,280 B
    __shared__ _Float16 ampT[32 * WSTR];      // 16,640 B (rows 30,31 uninit: cols 30,31 of acc unused)

    const int tid  = threadIdx.x;
    const int blk  = blockIdx.x;
    const int pg   = blk % NPG;               // fastest: consecutive blocks share amp slice (L2)
    const int s    = (blk / NPG) & (SS - 1);
    const int bc   = blk / (NPG * SS);        // b*CC + c

    const float* am = amp + (size_t)bc * (AA * SS * TT) + (size_t)s * TT;

    const float PI_F  = 3.14159265358979323846f;
    const float INV_H = 2.8647913f;           // 18 / (2*pi)
    const float H     = 0.34906585f;          // 2*pi / 18
    const float INV_T = 100.0f;

    const int wv   = tid >> 6;                // 0..3
    const int lane = tid & 63;
    const int mpl  = wv >> 1;                 // MFMA wave's local p
    const int mkh  = wv & 1;                  // MFMA wave's K-half of the chunk
    const int mrow = lane & 31;               // A n-row / B a-col
    const int mlh  = lane >> 5;

    f32x16 acc = {};

    for (int c = 0; c < NCH; ++c) {
        __syncthreads();                      // prev chunk's MFMA reads done

        // ---- phase 1a: zero W rows 0..17 (contiguous 4680 f16 = 585 uint4 per p)
        for (int i = tid; i < 2 * 585; i += NTH) {
            int pl = i / 585;
            int w  = i - pl * 585;
            ((uint4*)&Wl[pl][0])[w] = make_uint4(0u, 0u, 0u, 0u);
        }
        // ---- phase 1b: stage amp chunk transposed->f16: ampT[a][tt]
        for (int i = tid; i < AA * (TC / 4); i += NTH) {
            int a = i >> 6;                   // TC/4 == 64
            int q = i & 63;
            const float4 v = *(const float4*)&am[(size_t)a * (SS * TT) + c * TC + q * 4];
            half4_t h = { (_Float16)v.x, (_Float16)v.y, (_Float16)v.z, (_Float16)v.w };
            *(half4_t*)&ampT[a * WSTR + q * 4] = h;
        }
        __syncthreads();

        // ---- phase 2: top-2 softmax weights, scatter into dense W
        for (int k = 0; k < 2; ++k) {
            int it = tid + (k << 8);          // 0..511
            int pl = it >> 8;
            int tt = it & (TC - 1);
            int p  = pg * 2 + pl;
            float x = phase[((size_t)(bc * PP + p) * SS + s) * TT + c * TC + tt];
            float u = (x + PI_F) * INV_H;     // in [0, 18]
            int n0 = (int)floorf(u);
            n0 = n0 < 0 ? 0 : (n0 > NB - 1 ? NB - 1 : n0);
            float f  = u - (float)n0 - 0.5f;  // [-0.5, 0.5]
            float af = fabsf(f);
            int n1 = n0 + (f >= 0.0f ? 1 : -1);
            float e;
            if (n1 < 0) {                     // reference's unwrapped low edge: w1 ~ 7e-16
                e = 0.0f; n1 = NB;            // dump row (never read out)
            } else {
                if (n1 == NB) n1 = 0;         // positive wrap: same gap formula
                e = __expf(-(H * (1.0f - 2.0f * af)) * INV_T);
            }
            float w0 = 1.0f / (1.0f + e);
            float w1 = 1.0f - w0;
            Wl[pl][n0 * WSTR + tt] = (_Float16)w0;
            Wl[pl][n1 * WSTR + tt] = (_Float16)w1;
        }
        __syncthreads();

        // ---- phase 3: MFMA — wave (mpl, mkh): 8 K-steps of 32x32x16
        #pragma unroll
        for (int ks = 0; ks < 8; ++ks) {
            int t0 = mkh * 128 + ks * 16 + mlh * 8;
            const _Float16* Ab = &Wl[mpl][mrow * WSTR + t0];
            const _Float16* Bb = &ampT[mrow * WSTR + t0];
            half4_t a0 = *(const half4_t*)Ab;
            half4_t a1 = *(const half4_t*)(Ab + 4);
            half4_t b0 = *(const half4_t*)Bb;
            half4_t b1 = *(const half4_t*)(Bb + 4);
            half8_t av = __builtin_shufflevector(a0, a1, 0, 1, 2, 3, 4, 5, 6, 7);
            half8_t bv = __builtin_shufflevector(b0, b1, 0, 1, 2, 3, 4, 5, 6, 7);
            acc = __builtin_amdgcn_mfma_f32_32x32x16_f16(av, bv, acc, 0, 0, 0);
        }
    }
    __syncthreads();

    // ---- epilogue: acc -> LDS dist[2p][2kh][18][33], then entropy
    float* dist = (float*)&ampT[0];           // ampT dead; 4*18*33*4 = 9504 B
    #pragma unroll
    for (int r = 0; r < 16; ++r) {
        int row = (r & 3) + 8 * (r >> 2) + 4 * mlh;   // C/D: col=lane&31, this row formula (HW-verified)
        if (row < NB)
            dist[(((mpl << 1) | mkh) * NB + row) * 33 + mrow] = acc[r];
    }
    __syncthreads();

    if (tid < 2 * AA) {
        int pl = tid / AA;
        int a  = tid - pl * AA;
        float dn[NB], tot = 0.0f;
        #pragma unroll
        for (int n = 0; n < NB; ++n) {
            dn[n] = dist[((pl * 2 + 0) * NB + n) * 33 + a]
                  + dist[((pl * 2 + 1) * NB + n) * 33 + a];
            tot += dn[n];
        }
        float inv = 1.0f / (tot + 1e-10f);
        float ne = 0.0f;
        #pragma unroll
        for (int n = 0; n < NB; ++n) {
            float pv = fmaxf(dn[n] * inv, 1e-10f);
            ne += pv * logf(pv);
        }
        int p = pg * 2 + pl;
        out[((size_t)bc * SS + s) * (PP * AA) + p * AA + a] = 1.0f + ne * 0.345975362f; // 1/log(18)
    }
}

extern "C" void kernel_launch(void* const* d_in, const int* in_sizes, int n_in,
                              void* d_out, int out_size, void* d_ws, size_t ws_size,
                              hipStream_t stream)
{
    const float* phase = (const float*)d_in[0];
    const float* amp   = (const float*)d_in[1];
    float* out = (float*)d_out;
    dim3 grid(BB * CC * SS * NPG);   // 1280 blocks: (bc, s, p-pair)
    dim3 block(NTH);
    hipLaunchKernelGGL(mi_mfma_kernel, grid, block, 0, stream,
                       phase, amp, out);
}